// Round 6
// baseline (126.313 us; speedup 1.0000x reference)
//
#include <hip/hip_runtime.h>
#include <hip/hip_bf16.h>

typedef __attribute__((ext_vector_type(4))) float f32x4;
typedef __attribute__((ext_vector_type(4))) uint u32x4;
typedef __attribute__((ext_vector_type(8))) short bf16x8;

#define BM 128
#define BN 128
#define BK 64
#define NTHREADS 256
#define M_TOTAL 32768
#define N_TOTAL 1024
#define K_TOTAL 1024
#define NSTEPS (K_TOTAL / BK)

__device__ __forceinline__ uint pk2(float a, float b) {
  __hip_bfloat162 h = __float22bfloat162_rn(make_float2(a, b));  // v_cvt_pk_bf16_f32
  uint u;
  __builtin_memcpy(&u, &h, 4);
  return u;
}

// Barrier WITHOUT vmcnt drain (T4): ds-visibility via lgkmcnt(0) only; in-flight
// global prefetches cross the barrier and are waited (counted) at consumption.
// sched_barrier(0) pins ordering around the inline asm (methodology rule #18).
#define SOFT_BARRIER() do {                                                   \
    __builtin_amdgcn_sched_barrier(0);                                        \
    asm volatile("s_waitcnt lgkmcnt(0)" ::: "memory");                        \
    __builtin_amdgcn_s_barrier();                                             \
    __builtin_amdgcn_sched_barrier(0);                                        \
  } while (0)

// Macros (NOT lambdas: by-ref capture of arrays defeats SROA -> scratch;
// round-2 evidence VGPR_Count=52 + 2.24 GB scratch writes).

#define LOAD_TILE(kk) do {                                                    \
    const int si_ = a_idx ^ ((kk) >> 8);                                      \
    const float* Bsrc_ = (si_ == 0) ? Rm : (si_ == 1) ? Im                    \
                       : (si_ == 2) ? Jm : Km;                                \
    const int kloc_ = (kk) & 255;                                             \
    _Pragma("unroll")                                                         \
    for (int cc = 0; cc < 4; ++cc) {                                          \
      const float* pa_ = X + (size_t)(m0 + r0 + 32 * cc) * K_TOTAL + (kk) + k0;\
      rA[2 * cc]     = *(const f32x4*)pa_;                                    \
      rA[2 * cc + 1] = *(const f32x4*)(pa_ + 4);                              \
      const float* pb_ = Bsrc_ + (o_src + r0 + 32 * cc) * 256 + kloc_ + k0;   \
      rB[2 * cc]     = *(const f32x4*)pb_;                                    \
      rB[2 * cc + 1] = *(const f32x4*)(pb_ + 4);                              \
    }                                                                         \
  } while (0)

#define COMMIT_TILE(kk, dst) do {                                             \
    const uint neg_ = (0x284Eu >> ((a_idx << 2) | ((kk) >> 8))) & 1u;         \
    _Pragma("unroll")                                                         \
    for (int cc = 0; cc < 4; ++cc) {                                          \
      u32x4 va_;                                                              \
      va_[0] = pk2(rA[2 * cc][0], rA[2 * cc][1]);                             \
      va_[1] = pk2(rA[2 * cc][2], rA[2 * cc][3]);                             \
      va_[2] = pk2(rA[2 * cc + 1][0], rA[2 * cc + 1][1]);                     \
      va_[3] = pk2(rA[2 * cc + 1][2], rA[2 * cc + 1][3]);                     \
      *(u32x4*)((dst) + sbase + 4096 * cc) = va_;                             \
    }                                                                         \
    if (neg_) {                                                               \
      _Pragma("unroll")                                                       \
      for (int cc = 0; cc < 4; ++cc) {                                        \
        u32x4 vb_;                                                            \
        vb_[0] = pk2(-rB[2 * cc][0], -rB[2 * cc][1]);                         \
        vb_[1] = pk2(-rB[2 * cc][2], -rB[2 * cc][3]);                         \
        vb_[2] = pk2(-rB[2 * cc + 1][0], -rB[2 * cc + 1][1]);                 \
        vb_[3] = pk2(-rB[2 * cc + 1][2], -rB[2 * cc + 1][3]);                 \
        *(u32x4*)((dst) + 16384 + sbase + 4096 * cc) = vb_;                   \
      }                                                                       \
    } else {                                                                  \
      _Pragma("unroll")                                                       \
      for (int cc = 0; cc < 4; ++cc) {                                        \
        u32x4 vb_;                                                            \
        vb_[0] = pk2(rB[2 * cc][0], rB[2 * cc][1]);                           \
        vb_[1] = pk2(rB[2 * cc][2], rB[2 * cc][3]);                           \
        vb_[2] = pk2(rB[2 * cc + 1][0], rB[2 * cc + 1][1]);                   \
        vb_[3] = pk2(rB[2 * cc + 1][2], rB[2 * cc + 1][3]);                   \
        *(u32x4*)((dst) + 16384 + sbase + 4096 * cc) = vb_;                   \
      }                                                                       \
    }                                                                         \
  } while (0)

#define COMPUTE_TILE(src) do {                                                \
    _Pragma("unroll")                                                         \
    for (int ks = 0; ks < 2; ++ks) {                                          \
      const int kb_ = (ks << 6) + fkb;                                        \
      bf16x8 af_[4], bf_[4];                                                  \
      _Pragma("unroll")                                                       \
      for (int mi = 0; mi < 4; ++mi) {                                        \
        const int row_ = frow_a0 + (mi << 4);                                 \
        af_[mi] = *(const bf16x8*)((src) + row_ * (BK * 2)                    \
                                   + (kb_ ^ ((row_ & 7) << 4)));              \
      }                                                                       \
      _Pragma("unroll")                                                       \
      for (int ni = 0; ni < 4; ++ni) {                                        \
        const int row_ = frow_b0 + (ni << 4);                                 \
        bf_[ni] = *(const bf16x8*)((src) + 16384 + row_ * (BK * 2)            \
                                   + (kb_ ^ ((row_ & 7) << 4)));              \
      }                                                                       \
      _Pragma("unroll")                                                       \
      for (int mi = 0; mi < 4; ++mi)                                          \
        _Pragma("unroll")                                                     \
        for (int ni = 0; ni < 4; ++ni)                                        \
          acc[mi][ni] = __builtin_amdgcn_mfma_f32_16x16x32_bf16(              \
              af_[mi], bf_[ni], acc[mi][ni], 0, 0, 0);                        \
    }                                                                         \
  } while (0)

__global__ __launch_bounds__(NTHREADS, 2) void qlin_gemm(
    const float* __restrict__ X, const float* __restrict__ Rm,
    const float* __restrict__ Im, const float* __restrict__ Jm,
    const float* __restrict__ Km, const float* __restrict__ bias,
    float* __restrict__ Y)
{
  // 2048 blocks = 256 m-blocks x 8 n-blocks. XCD-bijective swizzle (2048%8==0),
  // n fastest within an XCD chunk so 8 n-blocks share each A-panel via L2.
  const int per = ((M_TOTAL / BM) * (N_TOTAL / BN)) >> 3;
  const int bid = (int)blockIdx.x;
  const int swz = (bid & 7) * per + (bid >> 3);
  const int m0 = (swz >> 3) * BM;
  const int n0 = (swz & 7) * BN;

  const int tid = (int)threadIdx.x;
  const int lane = tid & 63;
  const int wave = tid >> 6;
  const int wm = (wave >> 1) << 6;  // wave row origin: 0/64
  const int wn = (wave & 1) << 6;   // wave col origin: 0/64

  // Double-buffered: [buf][A|B][128*64] bf16 = 64 KB total -> 2 blocks/CU.
  __shared__ __align__(16) ushort sm[2 * 2 * BM * BK];
  char* const cS = (char*)sm;

  // Quaternion block structure: W[o,i] = sign(a,b) * S[a^b][o&255, i&255]
  // a = o>>8, b = i>>8 ; src index is XOR; sign mask bit (a*4+b) of 0x284E.
  const int a_idx = n0 >> 8;
  const int o_src = n0 & 255;

  // staging coords: thread stages 4 chunks of 8 elems; chunk cc -> row r0+32*cc.
  const int r0 = tid >> 3;        // 0..31
  const int k0 = (tid & 7) << 3;  // 0..56 (elems)
  const int sbase = r0 * (BK * 2) + ((k0 * 2) ^ ((r0 & 7) << 4));  // +4096*cc

  f32x4 rA[8], rB[8];
  f32x4 acc[4][4];
#pragma unroll
  for (int i = 0; i < 4; ++i)
#pragma unroll
    for (int j = 0; j < 4; ++j) acc[i][j] = (f32x4)(0.0f);

  const int frow_a0 = wm + (lane & 15);
  const int frow_b0 = wn + (lane & 15);
  const int fkb = (lane >> 4) << 4;  // 0,16,32,48 byte k-slot

  // ---- prologue: tile 0 into buf0, tile 1 loads left in flight ----
  LOAD_TILE(0);
  COMMIT_TILE(0, cS);
  LOAD_TILE(BK);
  SOFT_BARRIER();

  // ---- main loop: one NON-DRAINING barrier per K-step.
  //      commit(k+1) consumes loads issued a full iteration earlier (counted
  //      vmcnt at the cvt, not vmcnt(0) at the barrier); loads(k+2) stay in
  //      flight across the barrier; cvt-VALU + ds_write overlap MFMA. ----
#pragma unroll 1
  for (int k = 0; k < NSTEPS; ++k) {
    char* const rbuf = cS + ((k & 1) << 15);
    char* const wbuf = cS + (((k + 1) & 1) << 15);
    if (k + 1 < NSTEPS) COMMIT_TILE((k + 1) * BK, wbuf);
    if (k + 2 < NSTEPS) LOAD_TILE((k + 2) * BK);
    COMPUTE_TILE(rbuf);
    SOFT_BARRIER();
  }

  // epilogue: C/D layout col = lane&15, row = (lane>>4)*4 + reg  [m89-verified]
#pragma unroll
  for (int ni = 0; ni < 4; ++ni) {
    const int col = n0 + wn + (ni << 4) + (lane & 15);
    const float bv = bias[col];
#pragma unroll
    for (int mi = 0; mi < 4; ++mi) {
      const int r0e = m0 + wm + (mi << 4) + ((lane >> 4) << 2);
#pragma unroll
      for (int j = 0; j < 4; ++j)
        Y[(size_t)(r0e + j) * N_TOTAL + col] = acc[mi][ni][j] + bv;
    }
  }
}

extern "C" void kernel_launch(void* const* d_in, const int* in_sizes, int n_in,
                              void* d_out, int out_size, void* d_ws, size_t ws_size,
                              hipStream_t stream) {
  const float* X = (const float*)d_in[0];
  const float* Rm = (const float*)d_in[1];
  const float* Im = (const float*)d_in[2];
  const float* Jm = (const float*)d_in[3];
  const float* Km = (const float*)d_in[4];
  const float* bias = (const float*)d_in[5];
  float* Y = (float*)d_out;
  dim3 grid((M_TOTAL / BM) * (N_TOTAL / BN));
  qlin_gemm<<<grid, dim3(NTHREADS), 0, stream>>>(X, Rm, Im, Jm, Km, bias, Y);
}

// Round 7
// 116.623 us; speedup vs baseline: 1.0831x; 1.0831x over previous
//
#include <hip/hip_runtime.h>
#include <hip/hip_bf16.h>

typedef __attribute__((ext_vector_type(4))) float f32x4;
typedef __attribute__((ext_vector_type(4))) uint u32x4;
typedef __attribute__((ext_vector_type(8))) short bf16x8;

#define M_TOTAL 32768
#define N_TOTAL 1024
#define K_TOTAL 1024

__device__ __forceinline__ uint pk2(float a, float b) {
  __hip_bfloat162 h = __float22bfloat162_rn(make_float2(a, b));  // v_cvt_pk_bf16_f32
  uint u;
  __builtin_memcpy(&u, &h, 4);
  return u;
}

// Non-draining barrier (T4): ds visibility via lgkmcnt(0); global prefetches
// stay in flight across it (counted vmcnt at consumption). Rule #18 pinning.
#define SOFT_BARRIER() do {                                                   \
    __builtin_amdgcn_sched_barrier(0);                                        \
    asm volatile("s_waitcnt lgkmcnt(0)" ::: "memory");                        \
    __builtin_amdgcn_s_barrier();                                             \
    __builtin_amdgcn_sched_barrier(0);                                        \
  } while (0)

// ===========================================================================
// Pre-kernel: convert 4x 256x256 f32 S-matrices to fragment-major bf16 in ws.
// Fragment (si, cb, kb): 64 lanes x 16B contiguous; lane l holds
// S[cb*16 + (l&15)][kb*32 + (l>>4)*8 .. +7]  (matches MFMA frag layout).
// ===========================================================================
__global__ __launch_bounds__(256) void conv_b(
    const float* __restrict__ Rm, const float* __restrict__ Im,
    const float* __restrict__ Jm, const float* __restrict__ Km,
    ushort* __restrict__ ws)
{
  const int slot = blockIdx.x * 256 + threadIdx.x;  // 0..32767
  const int lane = slot & 63;
  const int kb = (slot >> 6) & 7;
  const int cb = (slot >> 9) & 15;
  const int si = slot >> 13;
  const float* S = (si == 0) ? Rm : (si == 1) ? Im : (si == 2) ? Jm : Km;
  const float* p = S + (cb * 16 + (lane & 15)) * 256 + kb * 32 + (lane >> 4) * 8;
  f32x4 lo = *(const f32x4*)p;
  f32x4 hi = *(const f32x4*)(p + 4);
  u32x4 v;
  v[0] = pk2(lo[0], lo[1]); v[1] = pk2(lo[2], lo[3]);
  v[2] = pk2(hi[0], hi[1]); v[3] = pk2(hi[2], hi[3]);
  *(u32x4*)(ws + (size_t)slot * 8) = v;
}

// ===========================================================================
// Main kernel: 256x256 tile, 8 waves (2 row-groups x 4 col-groups), BK=64.
// A: f32 -> reg -> cvt -> swizzled LDS (double-buffered, 64 KB).
// B: bf16 fragments direct from ws (L2-resident), sign via uniform XOR.
// ===========================================================================
#define BM2 256
#define BN2 256
#define BK2 64
#define NT2 512
#define NSTEPS2 (K_TOTAL / BK2)

#define LOAD_A2(kk) do {                                                      \
    _Pragma("unroll")                                                         \
    for (int cc = 0; cc < 4; ++cc) {                                          \
      const float* pa_ = X + (size_t)(m0 + r0 + 64 * cc) * K_TOTAL + (kk) + k0;\
      rA[2 * cc]     = *(const f32x4*)pa_;                                    \
      rA[2 * cc + 1] = *(const f32x4*)(pa_ + 4);                              \
    }                                                                         \
  } while (0)

#define COMMIT_A2(dst) do {                                                   \
    _Pragma("unroll")                                                         \
    for (int cc = 0; cc < 4; ++cc) {                                          \
      u32x4 va_;                                                              \
      va_[0] = pk2(rA[2 * cc][0], rA[2 * cc][1]);                             \
      va_[1] = pk2(rA[2 * cc][2], rA[2 * cc][3]);                             \
      va_[2] = pk2(rA[2 * cc + 1][0], rA[2 * cc + 1][1]);                     \
      va_[3] = pk2(rA[2 * cc + 1][2], rA[2 * cc + 1][3]);                     \
      *(u32x4*)((dst) + sbase + 8192 * cc) = va_;                             \
    }                                                                         \
  } while (0)

// Load 8 B-frags (2 ks x 4 ni) for K-step kk; apply sign by bf16 sign-bit XOR.
#define LOAD_B2(kk) do {                                                      \
    const int bsel_ = (kk) >> 8;                                              \
    const int si_ = a_idx ^ bsel_;                                            \
    const int kbq_ = ((kk) & 255) >> 5;                                       \
    const ushort* fb_ = WS + ((size_t)((si_ * 16 + wc4) * 8 + kbq_)) * 512    \
                        + lane * 8;                                           \
    _Pragma("unroll")                                                         \
    for (int ks = 0; ks < 2; ++ks)                                            \
      _Pragma("unroll")                                                       \
      for (int ni = 0; ni < 4; ++ni)                                          \
        bq[ks * 4 + ni] = *(const bf16x8*)(fb_ + (ni * 8 + ks) * 512);        \
    if ((0x284Eu >> ((a_idx << 2) | bsel_)) & 1u) {                           \
      _Pragma("unroll")                                                       \
      for (int f = 0; f < 8; ++f) {                                           \
        u32x4 u_ = __builtin_bit_cast(u32x4, bq[f]);                          \
        u_[0] ^= 0x80008000u; u_[1] ^= 0x80008000u;                           \
        u_[2] ^= 0x80008000u; u_[3] ^= 0x80008000u;                           \
        bq[f] = __builtin_bit_cast(bf16x8, u_);                               \
      }                                                                       \
    }                                                                         \
  } while (0)

#define COMPUTE2(src) do {                                                    \
    _Pragma("unroll")                                                         \
    for (int ks = 0; ks < 2; ++ks) {                                          \
      _Pragma("unroll")                                                       \
      for (int mi = 0; mi < 8; ++mi) {                                        \
        const int row_ = frow_a0 + (mi << 4);                                 \
        const int kb_ = (ks << 6) + fkb;                                      \
        bf16x8 af_ = *(const bf16x8*)((src) + row_ * (BK2 * 2)                \
                                      + (kb_ ^ ((row_ & 7) << 4)));           \
        _Pragma("unroll")                                                     \
        for (int ni = 0; ni < 4; ++ni)                                        \
          acc[mi][ni] = __builtin_amdgcn_mfma_f32_16x16x32_bf16(              \
              af_, bq[ks * 4 + ni], acc[mi][ni], 0, 0, 0);                    \
      }                                                                       \
    }                                                                         \
  } while (0)

__global__ __launch_bounds__(NT2, 2) void qlin_gemm2(
    const float* __restrict__ X, const ushort* __restrict__ WS,
    const float* __restrict__ bias, float* __restrict__ Y)
{
  // 512 blocks = 128 m-blocks x 4 n-blocks; XCD-bijective swizzle (512%8==0),
  // n fastest so the 4 n-blocks of an XCD chunk share A-panels in L2.
  const int per = ((M_TOTAL / BM2) * (N_TOTAL / BN2)) >> 3;  // 64
  const int bid = (int)blockIdx.x;
  const int swz = (bid & 7) * per + (bid >> 3);
  const int m0 = (swz >> 2) * BM2;
  const int nblk = swz & 3;
  const int n0 = nblk * BN2;
  const int a_idx = nblk;  // BN=256 -> a_idx == nblk; o_src == 0

  const int tid = (int)threadIdx.x;
  const int lane = tid & 63;
  const int wave = tid >> 6;
  const int wm = (wave >> 2) << 7;   // wave row origin: 0/128
  const int wc4 = (wave & 3) << 2;   // wave col-frag base (16-col units)

  __shared__ __align__(16) ushort smA[2 * BM2 * BK2];  // 64 KB dbuf
  char* const cS = (char*)smA;

  // A staging: thread stages 32 elems = 4 chunks of 8; rows r0 + 64*cc.
  const int r0 = tid >> 3;        // 0..63
  const int k0 = (tid & 7) << 3;  // 0..56
  const int sbase = r0 * (BK2 * 2) + ((k0 * 2) ^ ((r0 & 7) << 4));

  f32x4 rA[8];
  bf16x8 bq[8];
  f32x4 acc[8][4];
#pragma unroll
  for (int i = 0; i < 8; ++i)
#pragma unroll
    for (int j = 0; j < 4; ++j) acc[i][j] = (f32x4)(0.0f);

  const int frow_a0 = wm + (lane & 15);
  const int fkb = (lane >> 4) << 4;

  // prologue
  LOAD_A2(0);
  COMMIT_A2(cS);
  LOAD_A2(BK2);
  SOFT_BARRIER();

  // main loop: COMMIT_A(k+1) drains only A-loads; LOAD_B(k) issued BEFORE
  // LOAD_A(k+2) so compute's B-wait is vmcnt(16) with A still in flight.
#pragma unroll 1
  for (int k = 0; k < NSTEPS2; ++k) {
    char* const rbuf = cS + ((k & 1) << 15);
    char* const wbuf = cS + (((k + 1) & 1) << 15);
    if (k + 1 < NSTEPS2) { LOAD_A2((k + 1) * BK2); }  // consumed regs first:
    // NOTE: rA currently holds tile k+1 (loaded last iter) -> commit it, then
    // reuse rA for tile k+2.
    (void)0;
    // commit tile k+1 from rA
    if (k + 1 < NSTEPS2) { }
    COMMIT_A2(wbuf);                       // cvt rA(k+1) -> LDS (wbuf)
    LOAD_B2(k * BK2);                      // 8 frag loads (L2)
    if (k + 2 < NSTEPS2) LOAD_A2((k + 2) * BK2);  // prefetch A(k+2)
    COMPUTE2(rbuf);                        // 16 ds_read + 64 MFMA
    SOFT_BARRIER();
  }

  // epilogue: C/D layout col = lane&15, row = (lane>>4)*4 + reg  [m89-verified]
#pragma unroll
  for (int ni = 0; ni < 4; ++ni) {
    const int col = n0 + (wc4 << 4) + (ni << 4) + (lane & 15);
    const float bv = bias[col];
#pragma unroll
    for (int mi = 0; mi < 8; ++mi) {
      const int r0e = m0 + wm + (mi << 4) + ((lane >> 4) << 2);
#pragma unroll
      for (int j = 0; j < 4; ++j)
        Y[(size_t)(r0e + j) * N_TOTAL + col] = acc[mi][ni][j] + bv;
    }
  }
}

// ===========================================================================
// Fallback (proven round-6 kernel, 126 us) — used only if ws_size < 512 KB.
// ===========================================================================
#define BM 128
#define BN 128
#define BK 64
#define NTHREADS 256
#define NSTEPS (K_TOTAL / BK)

#define LOAD_TILE(kk) do {                                                    \
    const int si_ = a_idx ^ ((kk) >> 8);                                      \
    const float* Bsrc_ = (si_ == 0) ? Rm : (si_ == 1) ? Im                    \
                       : (si_ == 2) ? Jm : Km;                                \
    const int kloc_ = (kk) & 255;                                             \
    _Pragma("unroll")                                                         \
    for (int cc = 0; cc < 4; ++cc) {                                          \
      const float* pa_ = X + (size_t)(m0 + r0 + 32 * cc) * K_TOTAL + (kk) + k0;\
      rA[2 * cc]     = *(const f32x4*)pa_;                                    \
      rA[2 * cc + 1] = *(const f32x4*)(pa_ + 4);                              \
      const float* pb_ = Bsrc_ + (o_src + r0 + 32 * cc) * 256 + kloc_ + k0;   \
      rB[2 * cc]     = *(const f32x4*)pb_;                                    \
      rB[2 * cc + 1] = *(const f32x4*)(pb_ + 4);                              \
    }                                                                         \
  } while (0)

#define COMMIT_TILE(kk, dst) do {                                             \
    const uint neg_ = (0x284Eu >> ((a_idx << 2) | ((kk) >> 8))) & 1u;         \
    _Pragma("unroll")                                                         \
    for (int cc = 0; cc < 4; ++cc) {                                          \
      u32x4 va_;                                                              \
      va_[0] = pk2(rA[2 * cc][0], rA[2 * cc][1]);                             \
      va_[1] = pk2(rA[2 * cc][2], rA[2 * cc][3]);                             \
      va_[2] = pk2(rA[2 * cc + 1][0], rA[2 * cc + 1][1]);                     \
      va_[3] = pk2(rA[2 * cc + 1][2], rA[2 * cc + 1][3]);                     \
      *(u32x4*)((dst) + sbase + 4096 * cc) = va_;                             \
    }                                                                         \
    if (neg_) {                                                               \
      _Pragma("unroll")                                                       \
      for (int cc = 0; cc < 4; ++cc) {                                        \
        u32x4 vb_;                                                            \
        vb_[0] = pk2(-rB[2 * cc][0], -rB[2 * cc][1]);                         \
        vb_[1] = pk2(-rB[2 * cc][2], -rB[2 * cc][3]);                         \
        vb_[2] = pk2(-rB[2 * cc + 1][0], -rB[2 * cc + 1][1]);                 \
        vb_[3] = pk2(-rB[2 * cc + 1][2], -rB[2 * cc + 1][3]);                 \
        *(u32x4*)((dst) + 16384 + sbase + 4096 * cc) = vb_;                   \
      }                                                                       \
    } else {                                                                  \
      _Pragma("unroll")                                                       \
      for (int cc = 0; cc < 4; ++cc) {                                        \
        u32x4 vb_;                                                            \
        vb_[0] = pk2(rB[2 * cc][0], rB[2 * cc][1]);                           \
        vb_[1] = pk2(rB[2 * cc][2], rB[2 * cc][3]);                           \
        vb_[2] = pk2(rB[2 * cc + 1][0], rB[2 * cc + 1][1]);                   \
        vb_[3] = pk2(rB[2 * cc + 1][2], rB[2 * cc + 1][3]);                   \
        *(u32x4*)((dst) + 16384 + sbase + 4096 * cc) = vb_;                   \
      }                                                                       \
    }                                                                         \
  } while (0)

#define COMPUTE_TILE(src) do {                                                \
    _Pragma("unroll")                                                         \
    for (int ks = 0; ks < 2; ++ks) {                                          \
      const int kb_ = (ks << 6) + fkb;                                        \
      bf16x8 af_[4], bf_[4];                                                  \
      _Pragma("unroll")                                                       \
      for (int mi = 0; mi < 4; ++mi) {                                        \
        const int row_ = frow_a0 + (mi << 4);                                 \
        af_[mi] = *(const bf16x8*)((src) + row_ * (BK * 2)                    \
                                   + (kb_ ^ ((row_ & 7) << 4)));              \
      }                                                                       \
      _Pragma("unroll")                                                       \
      for (int ni = 0; ni < 4; ++ni) {                                        \
        const int row_ = frow_b0 + (ni << 4);                                 \
        bf_[ni] = *(const bf16x8*)((src) + 16384 + row_ * (BK * 2)            \
                                   + (kb_ ^ ((row_ & 7) << 4)));              \
      }                                                                       \
      _Pragma("unroll")                                                       \
      for (int mi = 0; mi < 4; ++mi)                                          \
        _Pragma("unroll")                                                     \
        for (int ni = 0; ni < 4; ++ni)                                        \
          acc[mi][ni] = __builtin_amdgcn_mfma_f32_16x16x32_bf16(              \
              af_[mi], bf_[ni], acc[mi][ni], 0, 0, 0);                        \
    }                                                                         \
  } while (0)

__global__ __launch_bounds__(NTHREADS, 2) void qlin_gemm(
    const float* __restrict__ X, const float* __restrict__ Rm,
    const float* __restrict__ Im, const float* __restrict__ Jm,
    const float* __restrict__ Km, const float* __restrict__ bias,
    float* __restrict__ Y)
{
  const int per = ((M_TOTAL / BM) * (N_TOTAL / BN)) >> 3;
  const int bid = (int)blockIdx.x;
  const int swz = (bid & 7) * per + (bid >> 3);
  const int m0 = (swz >> 3) * BM;
  const int n0 = (swz & 7) * BN;

  const int tid = (int)threadIdx.x;
  const int lane = tid & 63;
  const int wave = tid >> 6;
  const int wm = (wave >> 1) << 6;
  const int wn = (wave & 1) << 6;

  __shared__ __align__(16) ushort sm[2 * 2 * BM * BK];
  char* const cS = (char*)sm;

  const int a_idx = n0 >> 8;
  const int o_src = n0 & 255;

  const int r0 = tid >> 3;
  const int k0 = (tid & 7) << 3;
  const int sbase = r0 * (BK * 2) + ((k0 * 2) ^ ((r0 & 7) << 4));

  f32x4 rA[8], rB[8];
  f32x4 acc[4][4];
#pragma unroll
  for (int i = 0; i < 4; ++i)
#pragma unroll
    for (int j = 0; j < 4; ++j) acc[i][j] = (f32x4)(0.0f);

  const int frow_a0 = wm + (lane & 15);
  const int frow_b0 = wn + (lane & 15);
  const int fkb = (lane >> 4) << 4;

  LOAD_TILE(0);
  COMMIT_TILE(0, cS);
  LOAD_TILE(BK);
  SOFT_BARRIER();

#pragma unroll 1
  for (int k = 0; k < NSTEPS; ++k) {
    char* const rbuf = cS + ((k & 1) << 15);
    char* const wbuf = cS + (((k + 1) & 1) << 15);
    if (k + 1 < NSTEPS) COMMIT_TILE((k + 1) * BK, wbuf);
    if (k + 2 < NSTEPS) LOAD_TILE((k + 2) * BK);
    COMPUTE_TILE(rbuf);
    SOFT_BARRIER();
  }

#pragma unroll
  for (int ni = 0; ni < 4; ++ni) {
    const int col = n0 + wn + (ni << 4) + (lane & 15);
    const float bv = bias[col];
#pragma unroll
    for (int mi = 0; mi < 4; ++mi) {
      const int r0e = m0 + wm + (mi << 4) + ((lane >> 4) << 2);
#pragma unroll
      for (int j = 0; j < 4; ++j)
        Y[(size_t)(r0e + j) * N_TOTAL + col] = acc[mi][ni][j] + bv;
    }
  }
}

extern "C" void kernel_launch(void* const* d_in, const int* in_sizes, int n_in,
                              void* d_out, int out_size, void* d_ws, size_t ws_size,
                              hipStream_t stream) {
  const float* X = (const float*)d_in[0];
  const float* Rm = (const float*)d_in[1];
  const float* Im = (const float*)d_in[2];
  const float* Jm = (const float*)d_in[3];
  const float* Km = (const float*)d_in[4];
  const float* bias = (const float*)d_in[5];
  float* Y = (float*)d_out;

  if (ws_size >= (size_t)(4 * 256 * 256 * 2)) {  // 512 KB frag-major bf16 B
    ushort* ws = (ushort*)d_ws;
    conv_b<<<dim3(128), dim3(256), 0, stream>>>(Rm, Im, Jm, Km, ws);
    dim3 grid((M_TOTAL / BM2) * (N_TOTAL / BN2));  // 512
    qlin_gemm2<<<grid, dim3(NT2), 0, stream>>>(X, ws, bias, Y);
  } else {
    dim3 grid((M_TOTAL / BM) * (N_TOTAL / BN));    // 2048
    qlin_gemm<<<grid, dim3(NTHREADS), 0, stream>>>(X, Rm, Im, Jm, Km, bias, Y);
  }
}